// Round 1
// baseline (2844.235 us; speedup 1.0000x reference)
//
#include <hip/hip_runtime.h>
#include <hip/hip_fp16.h>

// GCN: out = relu( (X[i] + sum_{j in N(i)} X[j]) / deg[i] @ W )
// Pipeline (5 kernels):
//   init:      zero bucket cursors + edge-dtype detect
//   scatter:   bucket edges by (node>>7) into FIXED-CAPACITY regions
//              (owner_local<<20 | neighbor), block-aggregated reservations
//   wfrag:     pre-pack W (bf16) into MFMA B-operand fragment layout
//   gemm:      Y = X@W via mfma_f32_16x16x32_bf16, Y stored fp16
//   aggregate: one block per bucket; fp32 accumulators for 128 nodes in LDS
//              (64 KB), consumes UNSORTED bucket entries directly via
//              ds_add_f32 atomics. Degree via LDS histogram (1 atomic per
//              64 entries per wave). Replaces the old sort+gather pair.

#define DFEAT 128
#define BSH 7
#define BNODES (1 << BSH)   // 128 nodes per bucket
#define NBMAX 800           // >= ceil(100000/128)=782
#define EPB 8192            // edges per block in scatter
#define SORT_CAP 6144       // per-bucket capacity (mean 4096, sd 64)

typedef __attribute__((ext_vector_type(8))) short short8;
typedef __attribute__((ext_vector_type(4))) float f32x4;

__device__ __forceinline__ unsigned short f2bf(float x) {  // RNE
  unsigned u = __float_as_uint(x);
  return (unsigned short)((u + 0x7FFFu + ((u >> 16) & 1u)) >> 16);
}
__device__ __forceinline__ __half2 u2h(unsigned x) {
  union { unsigned u; __half2 h; } c; c.u = x; return c.h;
}

// ---------------- init: zero cursors + dtype detect ----------------
__global__ void init_kernel(const int* el32, int* gcur, int* flag, int NB) {
  int i = blockIdx.x * blockDim.x + threadIdx.x;
  if (i < NB) gcur[i] = 0;
  if (i == 0) flag[0] = (el32[1] == 0 && el32[3] == 0) ? 1 : 0;
}

__device__ __forceinline__ int edge_at(const void* el, long long i, int mode64) {
  if (mode64) return (int)((const long long*)el)[i];
  return ((const int*)el)[i];
}

// ---------------- block-aggregated bucketed scatter (8 edges/thread) -------
// Entry: (owner_local << 20) | neighbor   (n < 2^20)
__global__ __launch_bounds__(1024) void scatter_kernel(const void* el,
                                                       const int* __restrict__ flag,
                                                       int* __restrict__ gcur,
                                                       unsigned int* __restrict__ bucket,
                                                       int E, int NB) {
  __shared__ int lh[NBMAX];   // local counts, then local cursors
  __shared__ int lb[NBMAX];   // reserved bases within bucket region
  int t = threadIdx.x;
  for (int i = t; i < NB; i += 1024) lh[i] = 0;
  __syncthreads();
  int m = flag[0];
  long long e0 = (long long)blockIdx.x * EPB + t;
  int s[8], d[8];
#pragma unroll
  for (int r = 0; r < 8; r++) {
    long long e = e0 + r * 1024;
    if (e < E) {
      s[r] = edge_at(el, e, m);
      d[r] = edge_at(el, (long long)E + e, m);
    } else {
      s[r] = -1;
    }
  }
#pragma unroll
  for (int r = 0; r < 8; r++) {
    if (s[r] >= 0) {
      atomicAdd(&lh[s[r] >> BSH], 1);
      atomicAdd(&lh[d[r] >> BSH], 1);
    }
  }
  __syncthreads();
  for (int i = t; i < NB; i += 1024) {
    int c = lh[i];
    lb[i] = c ? atomicAdd(&gcur[i], c) : 0;  // cursors start at 0
  }
  __syncthreads();
  for (int i = t; i < NB; i += 1024) lh[i] = 0;
  __syncthreads();
#pragma unroll
  for (int r = 0; r < 8; r++) {
    if (s[r] >= 0) {
      int bs = s[r] >> BSH, bd = d[r] >> BSH;
      int ps = lb[bs] + atomicAdd(&lh[bs], 1);
      if (ps < SORT_CAP)
        bucket[(long long)bs * SORT_CAP + ps] =
            ((unsigned)(s[r] & (BNODES - 1)) << 20) | (unsigned)d[r];
      int pd = lb[bd] + atomicAdd(&lh[bd], 1);
      if (pd < SORT_CAP)
        bucket[(long long)bd * SORT_CAP + pd] =
            ((unsigned)(d[r] & (BNODES - 1)) << 20) | (unsigned)s[r];
    }
  }
}

// ---------------- W -> MFMA B-fragment layout (bf16) ----------------
__global__ __launch_bounds__(256) void wfrag_kernel(const float* __restrict__ W,
                                                    unsigned int* __restrict__ Wfrag) {
  int e = blockIdx.x * 256 + threadIdx.x;  // 0..2047
  if (e >= 2048) return;
  int lane = e & 63;
  int nt = (e >> 6) & 7;
  int kc = e >> 9;
  int k0 = kc * 32 + (lane >> 4) * 8;
  int col = nt * 16 + (lane & 15);
  unsigned int o[4];
#pragma unroll
  for (int jj = 0; jj < 4; jj++) {
    unsigned short lo = f2bf(W[(k0 + 2 * jj) * DFEAT + col]);
    unsigned short hi = f2bf(W[(k0 + 2 * jj + 1) * DFEAT + col]);
    o[jj] = (unsigned)lo | ((unsigned)hi << 16);
  }
  uint4* dst = (uint4*)Wfrag;
  uint4 v; v.x = o[0]; v.y = o[1]; v.z = o[2]; v.w = o[3];
  dst[e] = v;
}

// ---------------- Y = X @ W via MFMA bf16, output fp16 ----------------
__global__ __launch_bounds__(256) void gemm_kernel(const float* __restrict__ X,
                                                   const short8* __restrict__ Wfrag,
                                                   __half* __restrict__ Yh, int n) {
  int wave = threadIdx.x >> 6;
  int lane = threadIdx.x & 63;
  int row0 = (blockIdx.x * 4 + wave) * 16;
  if (row0 >= n) return;

  int rowA = row0 + (lane & 15);
  if (rowA >= n) rowA = n - 1;  // duplicate last row; stores guarded
  const float4* Xrow = (const float4*)(X + (long long)rowA * DFEAT);
  int koff = (lane >> 4) * 2;

  f32x4 acc[8];
#pragma unroll
  for (int ntp = 0; ntp < 8; ntp++) acc[ntp] = (f32x4){0.f, 0.f, 0.f, 0.f};

#pragma unroll
  for (int kc = 0; kc < 4; kc++) {
    float4 xa = Xrow[kc * 8 + koff];
    float4 xb = Xrow[kc * 8 + koff + 1];
    short8 a8;
    a8[0] = (short)f2bf(xa.x); a8[1] = (short)f2bf(xa.y);
    a8[2] = (short)f2bf(xa.z); a8[3] = (short)f2bf(xa.w);
    a8[4] = (short)f2bf(xb.x); a8[5] = (short)f2bf(xb.y);
    a8[6] = (short)f2bf(xb.z); a8[7] = (short)f2bf(xb.w);
#pragma unroll
    for (int nt = 0; nt < 8; nt++) {
      short8 b8 = Wfrag[(kc * 8 + nt) * 64 + lane];
      acc[nt] = __builtin_amdgcn_mfma_f32_16x16x32_bf16(a8, b8, acc[nt], 0, 0, 0);
    }
  }

  int rbase = row0 + (lane >> 4) * 4;
  int cbase = lane & 15;
#pragma unroll
  for (int nt = 0; nt < 8; nt++) {
#pragma unroll
    for (int r = 0; r < 4; r++) {
      int row = rbase + r;
      if (row < n)
        Yh[(long long)row * DFEAT + nt * 16 + cbase] = __float2half(acc[nt][r]);
    }
  }
}

// ---------------- aggregate: unsorted bucket -> LDS fp32 acc -> out -------
// One block per bucket (128 nodes). acc[128][128] fp32 in LDS (64 KB),
// initialized with the self row Y[i]. Each wave grabs 64 entries at a time
// (coalesced), histograms degree with ONE lds-atomic per 64 entries, then
// per entry: broadcast via shfl, load Y[nbr] row (256 B coalesced, 8 in
// flight), 2x ds_add_f32 into the owner's accumulator. Epilogue scales by
// 1/deg, relu, streams out fp32.
__global__ __launch_bounds__(1024) void aggregate_kernel(
    const unsigned int* __restrict__ bucket,
    const int* __restrict__ gcur,
    const unsigned int* __restrict__ Yh,   // half2 view
    float2* __restrict__ out2, int n) {
  __shared__ float acc[BNODES * DFEAT];  // 64 KB
  __shared__ int hdeg[BNODES];
  int b = blockIdx.x, t = threadIdx.x;
  int node0 = b << BSH;
  int nloc = n - node0; if (nloc > BNODES) nloc = BNODES;

  for (int i = t; i < BNODES; i += 1024) hdeg[i] = 0;
  // self term: acc[r][*] = Y[node0+r][*]
  for (int i = t; i < nloc * 64; i += 1024) {
    int r = i >> 6, c = i & 63;
    float2 f = __half22float2(u2h(Yh[(long long)(node0 + r) * 64 + c]));
    acc[r * DFEAT + 2 * c] = f.x;
    acc[r * DFEAT + 2 * c + 1] = f.y;
  }
  __syncthreads();

  int cnt = gcur[b]; if (cnt > SORT_CAP) cnt = SORT_CAP;
  long long base = (long long)b * SORT_CAP;
  int wave = t >> 6, lane = t & 63;

  for (int c0 = wave * 64; c0 < cnt; c0 += 16 * 64) {
    int m = cnt - c0; if (m > 64) m = 64;
    unsigned e = 0;
    if (lane < m) {
      e = bucket[base + c0 + lane];
      atomicAdd(&hdeg[e >> 20], 1);  // one DS atomic covers 64 entries' degrees
    }
    int tt = 0;
    for (; tt + 8 <= m; tt += 8) {
      unsigned v[8]; int ow[8];
#pragma unroll
      for (int u = 0; u < 8; u++) {
        unsigned ee = __shfl(e, tt + u);
        ow[u] = (int)(ee >> 20);
        v[u] = Yh[(long long)(ee & 0xFFFFFu) * 64 + lane];
      }
#pragma unroll
      for (int u = 0; u < 8; u++) {
        float2 f = __half22float2(u2h(v[u]));
        __hip_atomic_fetch_add(&acc[ow[u] * DFEAT + 2 * lane], f.x,
                               __ATOMIC_RELAXED, __HIP_MEMORY_SCOPE_WORKGROUP);
        __hip_atomic_fetch_add(&acc[ow[u] * DFEAT + 2 * lane + 1], f.y,
                               __ATOMIC_RELAXED, __HIP_MEMORY_SCOPE_WORKGROUP);
      }
    }
    for (; tt < m; tt++) {
      unsigned ee = __shfl(e, tt);
      int ow = (int)(ee >> 20);
      float2 f = __half22float2(u2h(Yh[(long long)(ee & 0xFFFFFu) * 64 + lane]));
      __hip_atomic_fetch_add(&acc[ow * DFEAT + 2 * lane], f.x,
                             __ATOMIC_RELAXED, __HIP_MEMORY_SCOPE_WORKGROUP);
      __hip_atomic_fetch_add(&acc[ow * DFEAT + 2 * lane + 1], f.y,
                             __ATOMIC_RELAXED, __HIP_MEMORY_SCOPE_WORKGROUP);
    }
  }
  __syncthreads();

  // epilogue: scale by 1/deg, relu, store fp32
  for (int i = t; i < nloc * 64; i += 1024) {
    int r = i >> 6, c = i & 63;
    float inv = 1.0f / (float)hdeg[r];
    float2 o;
    o.x = acc[r * DFEAT + 2 * c] * inv;
    o.y = acc[r * DFEAT + 2 * c + 1] * inv;
    o.x = o.x > 0.f ? o.x : 0.f;
    o.y = o.y > 0.f ? o.y : 0.f;
    out2[(long long)(node0 + r) * 64 + c] = o;
  }
}

// ---------------- launch ----------------
extern "C" void kernel_launch(void* const* d_in, const int* in_sizes, int n_in,
                              void* d_out, int out_size, void* d_ws, size_t ws_size,
                              hipStream_t stream) {
  const float* X = (const float*)d_in[0];
  const float* W = (const float*)d_in[1];
  const void* el = d_in[2];
  float* out = (float*)d_out;

  int n = in_sizes[0] / DFEAT;       // 100000
  int E = in_sizes[2] / 2;           // 1600000
  int NB = (n + BNODES - 1) >> BSH;  // 782

  char* p = (char*)d_ws;
  auto alloc = [&](size_t bytes) -> char* {
    char* q = p;
    p += (bytes + 511) & ~(size_t)511;
    return q;
  };
  int* gcur = (int*)alloc((size_t)NBMAX * 4);
  int* flag = (int*)alloc(64);
  unsigned int* bucket = (unsigned int*)alloc((size_t)NBMAX * SORT_CAP * 4);
  unsigned int* Wfrag = (unsigned int*)alloc((size_t)2048 * 16);
  __half* Yh = (__half*)alloc((size_t)n * DFEAT * 2);

  int eblocks = (E + EPB - 1) / EPB;

  init_kernel<<<(NBMAX + 255) / 256, 256, 0, stream>>>((const int*)el, gcur, flag, NB);
  scatter_kernel<<<eblocks, 1024, 0, stream>>>(el, flag, gcur, bucket, E, NB);
  wfrag_kernel<<<8, 256, 0, stream>>>(W, Wfrag);
  gemm_kernel<<<(n + 63) / 64, 256, 0, stream>>>(X, (const short8*)Wfrag, Yh, n);
  aggregate_kernel<<<NB, 1024, 0, stream>>>(bucket, gcur, (const unsigned int*)Yh,
                                            (float2*)out, n);
}

// Round 2
// 463.279 us; speedup vs baseline: 6.1394x; 6.1394x over previous
//
#include <hip/hip_runtime.h>
#include <hip/hip_fp16.h>

// GCN: out = relu( (X[i] + sum_{j in N(i)} X[j]) / deg[i] @ W )
// Pipeline (5 kernels):
//   init:    zero per-node degree cursors + edge-dtype detect
//   scatter: DIRECT per-node scatter: slot = atomicAdd(&dcur[node],1);
//            nbrs[node*96+slot] = neighbor. Replaces bucket scatter + sort.
//   wfrag:   pre-pack W (bf16) into MFMA B-operand fragment layout
//   gemm:    Y = X@W via mfma_f32_16x16x32_bf16, Y stored fp16
//   gather:  one wave per node, half2 packed accumulate, fp32 scale/relu out
//            (proven 107us engine; deg = dcur[node], list at node*96)

#define DFEAT 128
#define DEG_CAP 96   // mean deg 32, sd ~5.7; P(deg>96) ~ 1e-20

typedef __attribute__((ext_vector_type(8))) short short8;
typedef __attribute__((ext_vector_type(4))) float f32x4;

__device__ __forceinline__ unsigned short f2bf(float x) {  // RNE
  unsigned u = __float_as_uint(x);
  return (unsigned short)((u + 0x7FFFu + ((u >> 16) & 1u)) >> 16);
}
__device__ __forceinline__ __half2 u2h(unsigned x) {
  union { unsigned u; __half2 h; } c; c.u = x; return c.h;
}

// ---------------- init: zero cursors + dtype detect ----------------
__global__ void init_kernel(const int* el32, int* dcur, int* flag, int n) {
  int i = blockIdx.x * blockDim.x + threadIdx.x;
  if (i < n) dcur[i] = 0;
  if (i == 0) flag[0] = (el32[1] == 0 && el32[3] == 0) ? 1 : 0;
}

__device__ __forceinline__ int edge_at(const void* el, long long i, int mode64) {
  if (mode64) return (int)((const long long*)el)[i];
  return ((const int*)el)[i];
}

// ---------------- direct per-node scatter (8 edges/thread) ----------------
__global__ __launch_bounds__(256) void scatter_direct(const void* el,
                                                      const int* __restrict__ flag,
                                                      int* __restrict__ dcur,
                                                      int* __restrict__ nbrs,
                                                      int E) {
  int m = flag[0];
  long long i0 = (long long)blockIdx.x * (256 * 8) + threadIdx.x;
  int s[8], d[8];
#pragma unroll
  for (int r = 0; r < 8; r++) {
    long long e = i0 + r * 256;
    if (e < E) {
      s[r] = edge_at(el, e, m);
      d[r] = edge_at(el, (long long)E + e, m);
    } else {
      s[r] = -1;
    }
  }
#pragma unroll
  for (int r = 0; r < 8; r++) {
    if (s[r] >= 0) {
      int ps = atomicAdd(&dcur[s[r]], 1);
      if (ps < DEG_CAP) nbrs[(long long)s[r] * DEG_CAP + ps] = d[r];
      int pd = atomicAdd(&dcur[d[r]], 1);
      if (pd < DEG_CAP) nbrs[(long long)d[r] * DEG_CAP + pd] = s[r];
    }
  }
}

// ---------------- W -> MFMA B-fragment layout (bf16) ----------------
__global__ __launch_bounds__(256) void wfrag_kernel(const float* __restrict__ W,
                                                    unsigned int* __restrict__ Wfrag) {
  int e = blockIdx.x * 256 + threadIdx.x;  // 0..2047
  if (e >= 2048) return;
  int lane = e & 63;
  int nt = (e >> 6) & 7;
  int kc = e >> 9;
  int k0 = kc * 32 + (lane >> 4) * 8;
  int col = nt * 16 + (lane & 15);
  unsigned int o[4];
#pragma unroll
  for (int jj = 0; jj < 4; jj++) {
    unsigned short lo = f2bf(W[(k0 + 2 * jj) * DFEAT + col]);
    unsigned short hi = f2bf(W[(k0 + 2 * jj + 1) * DFEAT + col]);
    o[jj] = (unsigned)lo | ((unsigned)hi << 16);
  }
  uint4* dst = (uint4*)Wfrag;
  uint4 v; v.x = o[0]; v.y = o[1]; v.z = o[2]; v.w = o[3];
  dst[e] = v;
}

// ---------------- Y = X @ W via MFMA bf16, output fp16 ----------------
__global__ __launch_bounds__(256) void gemm_kernel(const float* __restrict__ X,
                                                   const short8* __restrict__ Wfrag,
                                                   __half* __restrict__ Yh, int n) {
  int wave = threadIdx.x >> 6;
  int lane = threadIdx.x & 63;
  int row0 = (blockIdx.x * 4 + wave) * 16;
  if (row0 >= n) return;

  int rowA = row0 + (lane & 15);
  if (rowA >= n) rowA = n - 1;  // duplicate last row; stores guarded
  const float4* Xrow = (const float4*)(X + (long long)rowA * DFEAT);
  int koff = (lane >> 4) * 2;

  f32x4 acc[8];
#pragma unroll
  for (int ntp = 0; ntp < 8; ntp++) acc[ntp] = (f32x4){0.f, 0.f, 0.f, 0.f};

#pragma unroll
  for (int kc = 0; kc < 4; kc++) {
    float4 xa = Xrow[kc * 8 + koff];
    float4 xb = Xrow[kc * 8 + koff + 1];
    short8 a8;
    a8[0] = (short)f2bf(xa.x); a8[1] = (short)f2bf(xa.y);
    a8[2] = (short)f2bf(xa.z); a8[3] = (short)f2bf(xa.w);
    a8[4] = (short)f2bf(xb.x); a8[5] = (short)f2bf(xb.y);
    a8[6] = (short)f2bf(xb.z); a8[7] = (short)f2bf(xb.w);
#pragma unroll
    for (int nt = 0; nt < 8; nt++) {
      short8 b8 = Wfrag[(kc * 8 + nt) * 64 + lane];
      acc[nt] = __builtin_amdgcn_mfma_f32_16x16x32_bf16(a8, b8, acc[nt], 0, 0, 0);
    }
  }

  int rbase = row0 + (lane >> 4) * 4;
  int cbase = lane & 15;
#pragma unroll
  for (int nt = 0; nt < 8; nt++) {
#pragma unroll
    for (int r = 0; r < 4; r++) {
      int row = rbase + r;
      if (row < n)
        Yh[(long long)row * DFEAT + nt * 16 + cbase] = __float2half(acc[nt][r]);
    }
  }
}

// ---------------- gather + scale + relu ----------------
// One wave per node; lane l owns features (2l, 2l+1) as one half2 (4 B load,
// one v_pk_add_f16 per row). Two accumulators relax the dep chain; unroll 8
// keeps 8 independent 256 B row loads in flight. No LDS.
__global__ __launch_bounds__(256) void gather_kernel(const unsigned int* __restrict__ Yh,
                                                     const int* __restrict__ dcur,
                                                     const int* __restrict__ nbrs,
                                                     float2* __restrict__ out2, int n) {
  int wid = (int)((blockIdx.x * (long long)blockDim.x + threadIdx.x) >> 6);
  int lane = threadIdx.x & 63;
  if (wid >= n) return;

  int len = dcur[wid];
  int lcap = len < DEG_CAP ? len : DEG_CAP;
  long long off0 = (long long)wid * DEG_CAP;
  __half2 acc0 = u2h(Yh[(long long)wid * 64 + lane]);  // self
  __half2 acc1 = u2h(0);

  for (int base = 0; base < lcap; base += 64) {
    int cnt = lcap - base; if (cnt > 64) cnt = 64;
    int idx = (lane < cnt) ? nbrs[off0 + base + lane] : 0;
    int t = 0;
    for (; t + 8 <= cnt; t += 8) {
      unsigned v[8];
#pragma unroll
      for (int u = 0; u < 8; u++) {
        int j = __shfl(idx, t + u);
        v[u] = Yh[(long long)j * 64 + lane];
      }
      acc0 = __hadd2(acc0, u2h(v[0])); acc1 = __hadd2(acc1, u2h(v[1]));
      acc0 = __hadd2(acc0, u2h(v[2])); acc1 = __hadd2(acc1, u2h(v[3]));
      acc0 = __hadd2(acc0, u2h(v[4])); acc1 = __hadd2(acc1, u2h(v[5]));
      acc0 = __hadd2(acc0, u2h(v[6])); acc1 = __hadd2(acc1, u2h(v[7]));
    }
    for (; t < cnt; t++) {
      int j = __shfl(idx, t);
      acc0 = __hadd2(acc0, u2h(Yh[(long long)j * 64 + lane]));
    }
  }

  float2 f0 = __half22float2(acc0);
  float2 f1 = __half22float2(acc1);
  float inv = 1.0f / (float)len;
  float2 o;
  o.x = (f0.x + f1.x) * inv;
  o.y = (f0.y + f1.y) * inv;
  o.x = o.x > 0.f ? o.x : 0.f;
  o.y = o.y > 0.f ? o.y : 0.f;
  out2[(long long)wid * 64 + lane] = o;
}

// ---------------- launch ----------------
extern "C" void kernel_launch(void* const* d_in, const int* in_sizes, int n_in,
                              void* d_out, int out_size, void* d_ws, size_t ws_size,
                              hipStream_t stream) {
  const float* X = (const float*)d_in[0];
  const float* W = (const float*)d_in[1];
  const void* el = d_in[2];
  float* out = (float*)d_out;

  int n = in_sizes[0] / DFEAT;  // 100000
  int E = in_sizes[2] / 2;      // 1600000

  char* p = (char*)d_ws;
  auto alloc = [&](size_t bytes) -> char* {
    char* q = p;
    p += (bytes + 511) & ~(size_t)511;
    return q;
  };
  int* dcur = (int*)alloc((size_t)n * 4);
  int* flag = (int*)alloc(64);
  int* nbrs = (int*)alloc((size_t)n * DEG_CAP * 4);
  unsigned int* Wfrag = (unsigned int*)alloc((size_t)2048 * 16);
  __half* Yh = (__half*)alloc((size_t)n * DFEAT * 2);

  int eblocks = (E + (256 * 8) - 1) / (256 * 8);

  init_kernel<<<(n + 255) / 256, 256, 0, stream>>>((const int*)el, dcur, flag, n);
  scatter_direct<<<eblocks, 256, 0, stream>>>(el, flag, dcur, nbrs, E);
  wfrag_kernel<<<8, 256, 0, stream>>>(W, Wfrag);
  gemm_kernel<<<(n + 63) / 64, 256, 0, stream>>>(X, (const short8*)Wfrag, Yh, n);
  gather_kernel<<<(n + 3) / 4, 256, 0, stream>>>((const unsigned int*)Yh, dcur, nbrs,
                                                 (float2*)out, n);
}

// Round 3
// 275.650 us; speedup vs baseline: 10.3183x; 1.6807x over previous
//
#include <hip/hip_runtime.h>
#include <hip/hip_fp16.h>

// GCN: out = relu( (X[i] + sum_{j in N(i)} X[j]) / deg[i] @ W )
// Pipeline (5 kernels):
//   init:    zero bucket cursors + edge-dtype detect
//   scatter: bucket edges by (node>>7) into FIXED-CAPACITY regions
//            (owner_local<<20 | neighbor), block-aggregated reservations
//            (compact writes -> no write amplification)
//   wfrag:   pre-pack W (bf16) into MFMA B-operand fragment layout
//   gemm:    Y = X@W via mfma_f32_16x16x32_bf16, Y stored fp16
//   gather_fused: one block per bucket; counting-sort the bucket's entries
//            in LDS (registers -> histogram -> scan -> srt[]), then 16 waves
//            x 8 nodes run the proven shfl-broadcast + half2 gather loop
//            reading adjacency from LDS. adj/start/deg never touch global.

#define DFEAT 128
#define BSH 7
#define BNODES (1 << BSH)   // 128 nodes per bucket
#define NBMAX 800           // >= ceil(100000/128)=782
#define EPB 8192            // edges per block in scatter
#define SORT_CAP 6144       // per-bucket capacity (mean 4096, sd 64)
#define EPT (SORT_CAP / 1024)  // entries per thread in fused sort = 6

typedef __attribute__((ext_vector_type(8))) short short8;
typedef __attribute__((ext_vector_type(4))) float f32x4;

__device__ __forceinline__ unsigned short f2bf(float x) {  // RNE
  unsigned u = __float_as_uint(x);
  return (unsigned short)((u + 0x7FFFu + ((u >> 16) & 1u)) >> 16);
}
__device__ __forceinline__ __half2 u2h(unsigned x) {
  union { unsigned u; __half2 h; } c; c.u = x; return c.h;
}

// ---------------- init: zero cursors + dtype detect ----------------
__global__ void init_kernel(const int* el32, int* gcur, int* flag, int NB) {
  int i = blockIdx.x * blockDim.x + threadIdx.x;
  if (i < NB) gcur[i] = 0;
  if (i == 0) flag[0] = (el32[1] == 0 && el32[3] == 0) ? 1 : 0;
}

__device__ __forceinline__ int edge_at(const void* el, long long i, int mode64) {
  if (mode64) return (int)((const long long*)el)[i];
  return ((const int*)el)[i];
}

// ---------------- block-aggregated bucketed scatter (8 edges/thread) -------
// Entry: (owner_local << 20) | neighbor   (n < 2^20)
__global__ __launch_bounds__(1024) void scatter_kernel(const void* el,
                                                       const int* __restrict__ flag,
                                                       int* __restrict__ gcur,
                                                       unsigned int* __restrict__ bucket,
                                                       int E, int NB) {
  __shared__ int lh[NBMAX];   // local counts, then local cursors
  __shared__ int lb[NBMAX];   // reserved bases within bucket region
  int t = threadIdx.x;
  for (int i = t; i < NB; i += 1024) lh[i] = 0;
  __syncthreads();
  int m = flag[0];
  long long e0 = (long long)blockIdx.x * EPB + t;
  int s[8], d[8];
#pragma unroll
  for (int r = 0; r < 8; r++) {
    long long e = e0 + r * 1024;
    if (e < E) {
      s[r] = edge_at(el, e, m);
      d[r] = edge_at(el, (long long)E + e, m);
    } else {
      s[r] = -1;
    }
  }
#pragma unroll
  for (int r = 0; r < 8; r++) {
    if (s[r] >= 0) {
      atomicAdd(&lh[s[r] >> BSH], 1);
      atomicAdd(&lh[d[r] >> BSH], 1);
    }
  }
  __syncthreads();
  for (int i = t; i < NB; i += 1024) {
    int c = lh[i];
    lb[i] = c ? atomicAdd(&gcur[i], c) : 0;  // cursors start at 0
  }
  __syncthreads();
  for (int i = t; i < NB; i += 1024) lh[i] = 0;
  __syncthreads();
#pragma unroll
  for (int r = 0; r < 8; r++) {
    if (s[r] >= 0) {
      int bs = s[r] >> BSH, bd = d[r] >> BSH;
      int ps = lb[bs] + atomicAdd(&lh[bs], 1);
      if (ps < SORT_CAP)
        bucket[(long long)bs * SORT_CAP + ps] =
            ((unsigned)(s[r] & (BNODES - 1)) << 20) | (unsigned)d[r];
      int pd = lb[bd] + atomicAdd(&lh[bd], 1);
      if (pd < SORT_CAP)
        bucket[(long long)bd * SORT_CAP + pd] =
            ((unsigned)(d[r] & (BNODES - 1)) << 20) | (unsigned)s[r];
    }
  }
}

// ---------------- W -> MFMA B-fragment layout (bf16) ----------------
__global__ __launch_bounds__(256) void wfrag_kernel(const float* __restrict__ W,
                                                    unsigned int* __restrict__ Wfrag) {
  int e = blockIdx.x * 256 + threadIdx.x;  // 0..2047
  if (e >= 2048) return;
  int lane = e & 63;
  int nt = (e >> 6) & 7;
  int kc = e >> 9;
  int k0 = kc * 32 + (lane >> 4) * 8;
  int col = nt * 16 + (lane & 15);
  unsigned int o[4];
#pragma unroll
  for (int jj = 0; jj < 4; jj++) {
    unsigned short lo = f2bf(W[(k0 + 2 * jj) * DFEAT + col]);
    unsigned short hi = f2bf(W[(k0 + 2 * jj + 1) * DFEAT + col]);
    o[jj] = (unsigned)lo | ((unsigned)hi << 16);
  }
  uint4* dst = (uint4*)Wfrag;
  uint4 v; v.x = o[0]; v.y = o[1]; v.z = o[2]; v.w = o[3];
  dst[e] = v;
}

// ---------------- Y = X @ W via MFMA bf16, output fp16 ----------------
__global__ __launch_bounds__(256) void gemm_kernel(const float* __restrict__ X,
                                                   const short8* __restrict__ Wfrag,
                                                   __half* __restrict__ Yh, int n) {
  int wave = threadIdx.x >> 6;
  int lane = threadIdx.x & 63;
  int row0 = (blockIdx.x * 4 + wave) * 16;
  if (row0 >= n) return;

  int rowA = row0 + (lane & 15);
  if (rowA >= n) rowA = n - 1;  // duplicate last row; stores guarded
  const float4* Xrow = (const float4*)(X + (long long)rowA * DFEAT);
  int koff = (lane >> 4) * 2;

  f32x4 acc[8];
#pragma unroll
  for (int ntp = 0; ntp < 8; ntp++) acc[ntp] = (f32x4){0.f, 0.f, 0.f, 0.f};

#pragma unroll
  for (int kc = 0; kc < 4; kc++) {
    float4 xa = Xrow[kc * 8 + koff];
    float4 xb = Xrow[kc * 8 + koff + 1];
    short8 a8;
    a8[0] = (short)f2bf(xa.x); a8[1] = (short)f2bf(xa.y);
    a8[2] = (short)f2bf(xa.z); a8[3] = (short)f2bf(xa.w);
    a8[4] = (short)f2bf(xb.x); a8[5] = (short)f2bf(xb.y);
    a8[6] = (short)f2bf(xb.z); a8[7] = (short)f2bf(xb.w);
#pragma unroll
    for (int nt = 0; nt < 8; nt++) {
      short8 b8 = Wfrag[(kc * 8 + nt) * 64 + lane];
      acc[nt] = __builtin_amdgcn_mfma_f32_16x16x32_bf16(a8, b8, acc[nt], 0, 0, 0);
    }
  }

  int rbase = row0 + (lane >> 4) * 4;
  int cbase = lane & 15;
#pragma unroll
  for (int nt = 0; nt < 8; nt++) {
#pragma unroll
    for (int r = 0; r < 4; r++) {
      int row = rbase + r;
      if (row < n)
        Yh[(long long)row * DFEAT + nt * 16 + cbase] = __float2half(acc[nt][r]);
    }
  }
}

// ---------------- fused counting-sort (LDS) + gather + scale + relu -------
// One block per bucket. Phase A: 1024 threads load <=6144 entries into
// registers (static 6-slot unroll), LDS histogram -> scan -> scatter into
// srt[]. Phase B: 16 waves x 8 nodes each; per node: self row + proven
// 8-deep shfl-broadcast half2 accumulate over LDS adjacency.
__global__ __launch_bounds__(1024) void gather_fused(
    const unsigned int* __restrict__ bucket,
    const int* __restrict__ gcur,
    const unsigned int* __restrict__ Yh,   // half2 view
    float2* __restrict__ out2, int n) {
  __shared__ int srt[SORT_CAP];  // 24 KB
  __shared__ int h[BNODES], pref[BNODES], cur[BNODES], scn[BNODES];
  int b = blockIdx.x, t = threadIdx.x;
  int cnt = gcur[b]; if (cnt > SORT_CAP) cnt = SORT_CAP;
  long long base = (long long)b * SORT_CAP;

  if (t < BNODES) h[t] = 0;
  __syncthreads();

  unsigned ent[EPT];
#pragma unroll
  for (int r = 0; r < EPT; r++) {
    int i = t + r * 1024;
    if (i < cnt) {
      unsigned e = bucket[base + i];
      ent[r] = e;
      atomicAdd(&h[e >> 20], 1);
    } else {
      ent[r] = 0xFFFFFFFFu;
    }
  }
  __syncthreads();

  int v = (t < BNODES) ? h[t] : 0;
  if (t < BNODES) scn[t] = v;
  __syncthreads();
  for (int dd = 1; dd < BNODES; dd <<= 1) {
    int a = (t < BNODES && t >= dd) ? scn[t - dd] : 0;
    __syncthreads();
    if (t < BNODES) scn[t] += a;
    __syncthreads();
  }
  if (t < BNODES) { pref[t] = scn[t] - v; cur[t] = scn[t] - v; }
  __syncthreads();

#pragma unroll
  for (int r = 0; r < EPT; r++) {
    unsigned e = ent[r];
    if (e != 0xFFFFFFFFu) {
      int p = atomicAdd(&cur[e >> 20], 1);
      srt[p] = (int)(e & 0xFFFFFu);
    }
  }
  __syncthreads();

  // ---- phase B: gather ----
  int wave = t >> 6, lane = t & 63;
  int node0 = b << BSH;
#pragma unroll 1
  for (int q = 0; q < 8; q++) {
    int r = wave * 8 + q;  // local node index 0..127
    int node = node0 + r;
    if (node >= n) break;
    int st = pref[r], len = h[r];
    __half2 acc0 = u2h(Yh[(long long)node * 64 + lane]);  // self
    __half2 acc1 = u2h(0);

    for (int bb = 0; bb < len; bb += 64) {
      int c2 = len - bb; if (c2 > 64) c2 = 64;
      int idx = (lane < c2) ? srt[st + bb + lane] : 0;
      int tt = 0;
      for (; tt + 8 <= c2; tt += 8) {
        unsigned vv[8];
#pragma unroll
        for (int u = 0; u < 8; u++) {
          int j = __shfl(idx, tt + u);
          vv[u] = Yh[(long long)j * 64 + lane];
        }
        acc0 = __hadd2(acc0, u2h(vv[0])); acc1 = __hadd2(acc1, u2h(vv[1]));
        acc0 = __hadd2(acc0, u2h(vv[2])); acc1 = __hadd2(acc1, u2h(vv[3]));
        acc0 = __hadd2(acc0, u2h(vv[4])); acc1 = __hadd2(acc1, u2h(vv[5]));
        acc0 = __hadd2(acc0, u2h(vv[6])); acc1 = __hadd2(acc1, u2h(vv[7]));
      }
      for (; tt < c2; tt++) {
        int j = __shfl(idx, tt);
        acc0 = __hadd2(acc0, u2h(Yh[(long long)j * 64 + lane]));
      }
    }

    float2 f0 = __half22float2(acc0);
    float2 f1 = __half22float2(acc1);
    float inv = 1.0f / (float)len;
    float2 o;
    o.x = (f0.x + f1.x) * inv;
    o.y = (f0.y + f1.y) * inv;
    o.x = o.x > 0.f ? o.x : 0.f;
    o.y = o.y > 0.f ? o.y : 0.f;
    out2[(long long)node * 64 + lane] = o;
  }
}

// ---------------- launch ----------------
extern "C" void kernel_launch(void* const* d_in, const int* in_sizes, int n_in,
                              void* d_out, int out_size, void* d_ws, size_t ws_size,
                              hipStream_t stream) {
  const float* X = (const float*)d_in[0];
  const float* W = (const float*)d_in[1];
  const void* el = d_in[2];
  float* out = (float*)d_out;

  int n = in_sizes[0] / DFEAT;       // 100000
  int E = in_sizes[2] / 2;           // 1600000
  int NB = (n + BNODES - 1) >> BSH;  // 782

  char* p = (char*)d_ws;
  auto alloc = [&](size_t bytes) -> char* {
    char* q = p;
    p += (bytes + 511) & ~(size_t)511;
    return q;
  };
  int* gcur = (int*)alloc((size_t)NBMAX * 4);
  int* flag = (int*)alloc(64);
  unsigned int* bucket = (unsigned int*)alloc((size_t)NBMAX * SORT_CAP * 4);
  unsigned int* Wfrag = (unsigned int*)alloc((size_t)2048 * 16);
  __half* Yh = (__half*)alloc((size_t)n * DFEAT * 2);

  int eblocks = (E + EPB - 1) / EPB;

  init_kernel<<<(NBMAX + 255) / 256, 256, 0, stream>>>((const int*)el, gcur, flag, NB);
  scatter_kernel<<<eblocks, 1024, 0, stream>>>(el, flag, gcur, bucket, E, NB);
  wfrag_kernel<<<8, 256, 0, stream>>>(W, Wfrag);
  gemm_kernel<<<(n + 63) / 64, 256, 0, stream>>>(X, (const short8*)Wfrag, Yh, n);
  gather_fused<<<NB, 1024, 0, stream>>>(bucket, gcur, (const unsigned int*)Yh,
                                        (float2*)out, n);
}

// Round 5
// 259.232 us; speedup vs baseline: 10.9718x; 1.0633x over previous
//
#include <hip/hip_runtime.h>
#include <hip/hip_fp16.h>

// GCN: out = relu( (X[i] + sum_{j in N(i)} X[j]) / deg[i] @ W )
// Pipeline (6 kernels):
//   init:    zero bucket cursors + edge-dtype detect
//   scatter: bucket edges by (node>>7), block-aggregated reservations
//            (EPB=4096 -> 391 blocks for occupancy)
//   sort:    per-bucket counting sort -> adj + per-node start/deg (15us)
//   wfrag:   pre-pack W (bf16) into MFMA B-operand fragment layout
//   gemm:    Y = X@W via mfma_f32_16x16x32_bf16, Y stored fp16
//   gather:  one wave per node, SPLIT-WAVE layout: lanes 0-31 / 32-63 own
//            DIFFERENT neighbor rows, 8 B uint2 loads (4 feats/lane),
//            512 B/wave/instr -> 2x in-flight bytes vs round-0. Half-sums
//            merged via shfl_xor(32); float4 coalesced store.

#define DFEAT 128
#define BSH 7
#define BNODES (1 << BSH)   // 128 nodes per bucket
#define NBMAX 800           // >= ceil(100000/128)=782
#define EPT_SC 4            // edges per thread in scatter
#define EPB (1024 * EPT_SC) // 4096 edges per block
#define SORT_CAP 6144       // per-bucket capacity (mean 4096, sd 64)

typedef __attribute__((ext_vector_type(8))) short short8;
typedef __attribute__((ext_vector_type(4))) float f32x4;

__device__ __forceinline__ unsigned short f2bf(float x) {  // RNE
  unsigned u = __float_as_uint(x);
  return (unsigned short)((u + 0x7FFFu + ((u >> 16) & 1u)) >> 16);
}
__device__ __forceinline__ __half2 u2h(unsigned x) {
  union { unsigned u; __half2 h; } c; c.u = x; return c.h;
}
__device__ __forceinline__ unsigned h2u(__half2 x) {
  union { __half2 h; unsigned u; } c; c.h = x; return c.u;
}

// ---------------- init: zero cursors + dtype detect ----------------
__global__ void init_kernel(const int* el32, int* gcur, int* flag, int NB) {
  int i = blockIdx.x * blockDim.x + threadIdx.x;
  if (i < NB) gcur[i] = 0;
  if (i == 0) flag[0] = (el32[1] == 0 && el32[3] == 0) ? 1 : 0;
}

__device__ __forceinline__ int edge_at(const void* el, long long i, int mode64) {
  if (mode64) return (int)((const long long*)el)[i];
  return ((const int*)el)[i];
}

// ---------------- block-aggregated bucketed scatter (4 edges/thread) -------
// Entry: (owner_local << 20) | neighbor   (n < 2^20)
__global__ __launch_bounds__(1024) void scatter_kernel(const void* el,
                                                       const int* __restrict__ flag,
                                                       int* __restrict__ gcur,
                                                       unsigned int* __restrict__ bucket,
                                                       int E, int NB) {
  __shared__ int lh[NBMAX];   // local counts, then local cursors
  __shared__ int lb[NBMAX];   // reserved bases within bucket region
  int t = threadIdx.x;
  for (int i = t; i < NB; i += 1024) lh[i] = 0;
  __syncthreads();
  int m = flag[0];
  long long e0 = (long long)blockIdx.x * EPB + t;
  int s[EPT_SC], d[EPT_SC];
#pragma unroll
  for (int r = 0; r < EPT_SC; r++) {
    long long e = e0 + r * 1024;
    if (e < E) {
      s[r] = edge_at(el, e, m);
      d[r] = edge_at(el, (long long)E + e, m);
    } else {
      s[r] = -1;
    }
  }
#pragma unroll
  for (int r = 0; r < EPT_SC; r++) {
    if (s[r] >= 0) {
      atomicAdd(&lh[s[r] >> BSH], 1);
      atomicAdd(&lh[d[r] >> BSH], 1);
    }
  }
  __syncthreads();
  for (int i = t; i < NB; i += 1024) {
    int c = lh[i];
    lb[i] = c ? atomicAdd(&gcur[i], c) : 0;  // cursors start at 0
  }
  __syncthreads();
  for (int i = t; i < NB; i += 1024) lh[i] = 0;
  __syncthreads();
#pragma unroll
  for (int r = 0; r < EPT_SC; r++) {
    if (s[r] >= 0) {
      int bs = s[r] >> BSH, bd = d[r] >> BSH;
      int ps = lb[bs] + atomicAdd(&lh[bs], 1);
      if (ps < SORT_CAP)
        bucket[(long long)bs * SORT_CAP + ps] =
            ((unsigned)(s[r] & (BNODES - 1)) << 20) | (unsigned)d[r];
      int pd = lb[bd] + atomicAdd(&lh[bd], 1);
      if (pd < SORT_CAP)
        bucket[(long long)bd * SORT_CAP + pd] =
            ((unsigned)(d[r] & (BNODES - 1)) << 20) | (unsigned)s[r];
    }
  }
}

// ---------------- per-bucket counting sort -> adj + start/deg --------------
__global__ __launch_bounds__(1024) void sort_kernel(const unsigned int* __restrict__ bucket,
                                                    const int* __restrict__ gcur,
                                                    int* __restrict__ adj,
                                                    int* __restrict__ start,
                                                    int* __restrict__ degg,
                                                    int n) {
  __shared__ int srt[SORT_CAP];  // 24 KB
  __shared__ int h[BNODES], pref[BNODES], cur[BNODES], scn[BNODES];
  int b = blockIdx.x, t = threadIdx.x;
  int cnt = gcur[b]; if (cnt > SORT_CAP) cnt = SORT_CAP;
  long long base = (long long)b * SORT_CAP;

  if (t < BNODES) h[t] = 0;
  __syncthreads();
  for (int i = t; i < cnt; i += 1024)
    atomicAdd(&h[bucket[base + i] >> 20], 1);
  __syncthreads();
  int v = (t < BNODES) ? h[t] : 0;
  if (t < BNODES) scn[t] = v;
  __syncthreads();
  for (int dd = 1; dd < BNODES; dd <<= 1) {
    int a = (t < BNODES && t >= dd) ? scn[t - dd] : 0;
    __syncthreads();
    if (t < BNODES) scn[t] += a;
    __syncthreads();
  }
  if (t < BNODES) { pref[t] = scn[t] - v; cur[t] = scn[t] - v; }
  __syncthreads();
  for (int i = t; i < cnt; i += 1024) {
    unsigned e = bucket[base + i];
    int p = atomicAdd(&cur[e >> 20], 1);
    srt[p] = (int)(e & 0xFFFFFu);
  }
  __syncthreads();
  for (int i = t; i < cnt; i += 1024) adj[base + i] = srt[i];
  int node = (b << BSH) + t;
  if (t < BNODES && node < n) {
    start[node] = (int)(base + pref[t]);
    degg[node] = h[t];
  }
}

// ---------------- W -> MFMA B-fragment layout (bf16) ----------------
__global__ __launch_bounds__(256) void wfrag_kernel(const float* __restrict__ W,
                                                    unsigned int* __restrict__ Wfrag) {
  int e = blockIdx.x * 256 + threadIdx.x;  // 0..2047
  if (e >= 2048) return;
  int lane = e & 63;
  int nt = (e >> 6) & 7;
  int kc = e >> 9;
  int k0 = kc * 32 + (lane >> 4) * 8;
  int col = nt * 16 + (lane & 15);
  unsigned int o[4];
#pragma unroll
  for (int jj = 0; jj < 4; jj++) {
    unsigned short lo = f2bf(W[(k0 + 2 * jj) * DFEAT + col]);
    unsigned short hi = f2bf(W[(k0 + 2 * jj + 1) * DFEAT + col]);
    o[jj] = (unsigned)lo | ((unsigned)hi << 16);
  }
  uint4* dst = (uint4*)Wfrag;
  uint4 v; v.x = o[0]; v.y = o[1]; v.z = o[2]; v.w = o[3];
  dst[e] = v;
}

// ---------------- Y = X @ W via MFMA bf16, output fp16 ----------------
__global__ __launch_bounds__(256) void gemm_kernel(const float* __restrict__ X,
                                                   const short8* __restrict__ Wfrag,
                                                   __half* __restrict__ Yh, int n) {
  int wave = threadIdx.x >> 6;
  int lane = threadIdx.x & 63;
  int row0 = (blockIdx.x * 4 + wave) * 16;
  if (row0 >= n) return;

  int rowA = row0 + (lane & 15);
  if (rowA >= n) rowA = n - 1;  // duplicate last row; stores guarded
  const float4* Xrow = (const float4*)(X + (long long)rowA * DFEAT);
  int koff = (lane >> 4) * 2;

  f32x4 acc[8];
#pragma unroll
  for (int ntp = 0; ntp < 8; ntp++) acc[ntp] = (f32x4){0.f, 0.f, 0.f, 0.f};

#pragma unroll
  for (int kc = 0; kc < 4; kc++) {
    float4 xa = Xrow[kc * 8 + koff];
    float4 xb = Xrow[kc * 8 + koff + 1];
    short8 a8;
    a8[0] = (short)f2bf(xa.x); a8[1] = (short)f2bf(xa.y);
    a8[2] = (short)f2bf(xa.z); a8[3] = (short)f2bf(xa.w);
    a8[4] = (short)f2bf(xb.x); a8[5] = (short)f2bf(xb.y);
    a8[6] = (short)f2bf(xb.z); a8[7] = (short)f2bf(xb.w);
#pragma unroll
    for (int nt = 0; nt < 8; nt++) {
      short8 b8 = Wfrag[(kc * 8 + nt) * 64 + lane];
      acc[nt] = __builtin_amdgcn_mfma_f32_16x16x32_bf16(a8, b8, acc[nt], 0, 0, 0);
    }
  }

  int rbase = row0 + (lane >> 4) * 4;
  int cbase = lane & 15;
#pragma unroll
  for (int nt = 0; nt < 8; nt++) {
#pragma unroll
    for (int r = 0; r < 4; r++) {
      int row = rbase + r;
      if (row < n)
        Yh[(long long)row * DFEAT + nt * 16 + cbase] = __float2half(acc[nt][r]);
    }
  }
}

// ---------------- gather + scale + relu (split-wave uint2 loads) ----------
// One wave per node. Lanes 0-31 and 32-63 each own a DIFFERENT neighbor row;
// lane loads uint2 (features 4c..4c+3 of its row) -> 512 B/wave/instruction,
// 2x the in-flight bytes of the 4 B variant. 4 fp16 accumulators; half-wave
// sums merged with shfl_xor(32); self row added last; lanes 0-31 store
// float4 (fully coalesced 512 B/row).
__global__ __launch_bounds__(256) void gather_kernel(const uint2* __restrict__ Yh2,
                                                     const int* __restrict__ start,
                                                     const int* __restrict__ degg,
                                                     const int* __restrict__ adj,
                                                     float4* __restrict__ out4, int n) {
  int wid = (int)((blockIdx.x * (long long)blockDim.x + threadIdx.x) >> 6);
  int lane = threadIdx.x & 63;
  if (wid >= n) return;

  int off0 = start[wid], len = degg[wid];
  int c = lane & 31;
  int half = lane >> 5;
  __half2 acc0 = u2h(0), acc1 = u2h(0), acc2 = u2h(0), acc3 = u2h(0);

  for (int base = 0; base < len; base += 64) {
    int cnt = len - base; if (cnt > 64) cnt = 64;
    int idx = (lane < cnt) ? adj[off0 + base + lane] : 0;
    int tt = 0;
    for (; tt + 16 <= cnt; tt += 16) {  // 16 rows per iter, 8 loads in flight
      uint2 v[8];
#pragma unroll
      for (int u = 0; u < 8; u++) {
        int j = __shfl(idx, tt + 2 * u + half);
        v[u] = Yh2[(long long)j * 32 + c];
      }
      acc0 = __hadd2(acc0, u2h(v[0].x)); acc1 = __hadd2(acc1, u2h(v[0].y));
      acc2 = __hadd2(acc2, u2h(v[1].x)); acc3 = __hadd2(acc3, u2h(v[1].y));
      acc0 = __hadd2(acc0, u2h(v[2].x)); acc1 = __hadd2(acc1, u2h(v[2].y));
      acc2 = __hadd2(acc2, u2h(v[3].x)); acc3 = __hadd2(acc3, u2h(v[3].y));
      acc0 = __hadd2(acc0, u2h(v[4].x)); acc1 = __hadd2(acc1, u2h(v[4].y));
      acc2 = __hadd2(acc2, u2h(v[5].x)); acc3 = __hadd2(acc3, u2h(v[5].y));
      acc0 = __hadd2(acc0, u2h(v[6].x)); acc1 = __hadd2(acc1, u2h(v[6].y));
      acc2 = __hadd2(acc2, u2h(v[7].x)); acc3 = __hadd2(acc3, u2h(v[7].y));
    }
    for (; tt + 2 <= cnt; tt += 2) {  // pair tail
      int j = __shfl(idx, tt + half);
      uint2 v = Yh2[(long long)j * 32 + c];
      acc0 = __hadd2(acc0, u2h(v.x)); acc1 = __hadd2(acc1, u2h(v.y));
    }
    if (tt < cnt) {  // odd tail: both halves load same row; zero the upper
      int j = __shfl(idx, tt);
      uint2 v = Yh2[(long long)j * 32 + c];
      if (half) { v.x = 0; v.y = 0; }
      acc2 = __hadd2(acc2, u2h(v.x)); acc3 = __hadd2(acc3, u2h(v.y));
    }
  }

  acc0 = __hadd2(acc0, acc2);
  acc1 = __hadd2(acc1, acc3);
  // merge the two half-wave partial sums
  acc0 = __hadd2(acc0, u2h((unsigned)__shfl_xor((int)h2u(acc0), 32)));
  acc1 = __hadd2(acc1, u2h((unsigned)__shfl_xor((int)h2u(acc1), 32)));
  // self row
  uint2 sv = Yh2[(long long)wid * 32 + c];
  acc0 = __hadd2(acc0, u2h(sv.x));
  acc1 = __hadd2(acc1, u2h(sv.y));

  if (half == 0) {
    float2 f0 = __half22float2(acc0);
    float2 f1 = __half22float2(acc1);
    float inv = 1.0f / (float)len;
    float4 o;
    o.x = f0.x * inv; o.y = f0.y * inv; o.z = f1.x * inv; o.w = f1.y * inv;
    o.x = o.x > 0.f ? o.x : 0.f;
    o.y = o.y > 0.f ? o.y : 0.f;
    o.z = o.z > 0.f ? o.z : 0.f;
    o.w = o.w > 0.f ? o.w : 0.f;
    out4[(long long)wid * 32 + c] = o;
  }
}

// ---------------- launch ----------------
extern "C" void kernel_launch(void* const* d_in, const int* in_sizes, int n_in,
                              void* d_out, int out_size, void* d_ws, size_t ws_size,
                              hipStream_t stream) {
  const float* X = (const float*)d_in[0];
  const float* W = (const float*)d_in[1];
  const void* el = d_in[2];
  float* out = (float*)d_out;

  int n = in_sizes[0] / DFEAT;       // 100000
  int E = in_sizes[2] / 2;           // 1600000
  int NB = (n + BNODES - 1) >> BSH;  // 782

  char* p = (char*)d_ws;
  auto alloc = [&](size_t bytes) -> char* {
    char* q = p;
    p += (bytes + 511) & ~(size_t)511;
    return q;
  };
  int* gcur = (int*)alloc((size_t)NBMAX * 4);
  int* flag = (int*)alloc(64);
  unsigned int* bucket = (unsigned int*)alloc((size_t)NBMAX * SORT_CAP * 4);
  int* adj   = (int*)alloc((size_t)NBMAX * SORT_CAP * 4);
  int* start = (int*)alloc((size_t)n * 4);
  int* degg  = (int*)alloc((size_t)n * 4);
  unsigned int* Wfrag = (unsigned int*)alloc((size_t)2048 * 16);
  __half* Yh = (__half*)alloc((size_t)n * DFEAT * 2);

  int eblocks = (E + EPB - 1) / EPB;

  init_kernel<<<(NBMAX + 255) / 256, 256, 0, stream>>>((const int*)el, gcur, flag, NB);
  scatter_kernel<<<eblocks, 1024, 0, stream>>>(el, flag, gcur, bucket, E, NB);
  sort_kernel<<<NB, 1024, 0, stream>>>(bucket, gcur, adj, start, degg, n);
  wfrag_kernel<<<8, 256, 0, stream>>>(W, Wfrag);
  gemm_kernel<<<(n + 63) / 64, 256, 0, stream>>>(X, (const short8*)Wfrag, Yh, n);
  gather_kernel<<<(n + 3) / 4, 256, 0, stream>>>((const uint2*)Yh, start, degg, adj,
                                                 (float4*)out, n);
}